// Round 2
// baseline (306.121 us; speedup 1.0000x reference)
//
#include <hip/hip_runtime.h>
#include <math.h>

// SingleRoIExtractor: 4-level FPN RoIAlign (mmdet legacy, aligned=False)
// Block = (roi, 64-channel group). Ring-2 LDS buffers, one barrier/channel,
// depth-4 global register prefetch (loads for ch c+5 issued at iter c).
// KEY (R2): __syncthreads() compiles to s_waitcnt vmcnt(0) before s_barrier,
// draining the prefetch queue every iteration (defeats the ring). Replaced
// with lgkmcnt(0)-only + raw s_barrier (T4 idiom): ds_writes made visible,
// global prefetch loads stay in flight across barriers (counted vmcnt at
// their 4-iterations-later use).
// Staging: 16B-aligned float4 global loads -> ds_write_b128 (levels 0-2;
// level 3 W=38 -> float2/b64). LDS row slot = cpr*V floats (bump +V if
// multiple of 32 to avoid row-aligned banks).
// x-interp reads L[p],L[p+1] unconditionally; overrun hits next-row data
// (weight 0) or zeroed pad/sentinel.
// Worst patch (h<=600 => rows<=141, stride 12) = 1704 floats -> LDS_N=1920.
// 2*1920*4B = 15 KB/block -> 8 blocks/CU (thread-limited anyway).
// Channel loop hand-unrolled x4 so the 4 prefetch register sets are
// statically indexed (runtime-indexed register arrays spill to scratch).

#define OUT_SZ 7
#define NCH 256
#define NBINS 49
#define CGC 64
#define NGROUPS 4
#define LDS_N 1920

// Workgroup barrier WITHOUT the vmcnt(0) drain __syncthreads() carries.
// lgkmcnt(0): our ds_writes are visible to the CU before we signal arrival.
// "memory" clobbers stop the compiler moving LDS ops across the barrier.
#define WG_BARRIER_LDS()                                        \
    do {                                                        \
        asm volatile("s_waitcnt lgkmcnt(0)" ::: "memory");      \
        __builtin_amdgcn_s_barrier();                           \
        asm volatile("" ::: "memory");                          \
    } while (0)

template<int VSH>
__device__ __forceinline__ void roi_group(
    const float* __restrict__ cbase, int CLrel, int HW, int H, int W,
    float x1, float y1, float bw, float bh,
    int t, float* __restrict__ outk, float (*lds)[LDS_N])
{
    const int V = 1 << VSH;
    const float fH = (float)H, fW = (float)W;

    // ---- patch bounds from first/last samples (monotonic in sample idx) ----
    float xf0 = fminf(fmaxf(x1 + 0.25f * bw, 0.0f), fW - 1.0f);
    float xfl = fminf(fmaxf(x1 + 6.75f * bw, 0.0f), fW - 1.0f);
    int xa = (int)floorf(xf0);
    int xb = min((int)floorf(xfl) + 1, W - 1);
    float yf0 = fminf(fmaxf(y1 + 0.25f * bh, 0.0f), fH - 1.0f);
    float yfl = fminf(fmaxf(y1 + 6.75f * bh, 0.0f), fH - 1.0f);
    int ya = (int)floorf(yf0);
    int yb = min((int)floorf(yfl) + 1, H - 1);

    int axa    = xa & ~(V - 1);            // aligned col base
    int cpr    = ((xb - axa) >> VSH) + 1;  // chunks per row
    int rowlen = cpr << VSH;
    int stride = rowlen + (((rowlen & 31) == 0) ? V : 0);  // keep V-aligned, break 32-multiples
    int Rows   = yb - ya + 1;
    int C      = Rows * cpr;               // total chunks

    // ---- zero sentinel + pad (targets of weight-0 overrun reads) ----
    {
        int sent = Rows * stride;          // <= ~1704 < LDS_N
        if (t == 0) { lds[0][sent] = 0.0f; lds[1][sent] = 0.0f; }
        int padw = stride - rowlen;
        if (padw) {
            int np = Rows * padw;
            for (int z = t; z < np; z += 256) {
                int zr = z / padw, zc = z - zr * padw;
                int idx = zr * stride + rowlen + zc;
                lds[0][idx] = 0.0f;
                lds[1][idx] = 0.0f;
            }
        }
    }

    // ---- staging chunk assignment (rotated: lanes >=196 take chunks first) ----
    int q0 = (t + 60) & 255;
    int goff[2], loff[2];
    bool act[2];
#pragma unroll
    for (int i = 0; i < 2; ++i) {
        int q = q0 + 256 * i;
        act[i] = q < C;
        int qq = act[i] ? q : 0;
        int r  = qq / cpr;
        int j  = qq - r * cpr;
        int rowbase = (ya + r) * W;
        int rel  = rowbase + axa + (j << VSH);
        int relc = min(rel, CLrel);        // tensor-end clamp, V-aligned
        goff[i] = relc;
        loff[i] = r * stride + (relc - rowbase - axa);
    }

    // ---- sample params (threads 0..195: bin = t>>2, sample = t&3) ----
    int bin = t >> 2;
    int s   = t & 3;
    int oy  = bin / OUT_SZ;
    int ox  = bin - oy * OUT_SZ;

    float xs  = x1 + ((float)(2 * ox + (s & 1)) + 0.5f) * 0.5f * bw;
    float ysv = y1 + ((float)(2 * oy + (s >> 1)) + 0.5f) * 0.5f * bh;
    bool vall = (xs >= -1.0f) && (xs <= fW) && (ysv >= -1.0f) && (ysv <= fH);

    float xc = fminf(fmaxf(xs, 0.0f), fW - 1.0f);
    float yc = fminf(fmaxf(ysv, 0.0f), fH - 1.0f);
    float xflr = floorf(xc), yflr = floorf(yc);
    int x0 = (int)xflr, y0 = (int)yflr;
    float lx = xc - xflr, ly = yc - yflr;

    int p0 = (y0 - ya) * stride + (x0 - axa);
    int ry = min(y0 + 1 - ya, Rows - 1);   // y clamp (x handled by overrun+w=0)
    int p1 = ry * stride + (x0 - axa);

    float w00 = (1.0f - ly) * (1.0f - lx);
    float w01 = (1.0f - ly) * lx;
    float w10 = ly * (1.0f - lx);
    float w11 = ly * lx;

    auto ldchunk = [&](const float* p, int i) -> float4 {
        if (!act[i]) return make_float4(0.f, 0.f, 0.f, 0.f);
        if (VSH == 2) return *(const float4*)(p + goff[i]);
        float2 h2 = *(const float2*)(p + goff[i]);
        return make_float4(h2.x, h2.y, 0.f, 0.f);
    };
    auto stchunk = [&](float* dst, int i, float4 v) {
        if (act[i]) {
            if (VSH == 2) *(float4*)(dst + loff[i]) = v;
            else          *(float2*)(dst + loff[i]) = make_float2(v.x, v.y);
        }
    };

    // ---- prologue: ch0 -> buf0; ch1..ch4 -> pv1,pv2,pv3,pv0 ----
    // Register ring: channel m lives in set (m & 3). Depth-4 in flight.
    float4 pv0[2], pv1[2], pv2[2], pv3[2], t0[2];
    t0[0]  = ldchunk(cbase, 0);
    pv1[0] = ldchunk(cbase + (size_t)HW, 0);
    pv2[0] = ldchunk(cbase + 2 * (size_t)HW, 0);
    pv3[0] = ldchunk(cbase + 3 * (size_t)HW, 0);
    pv0[0] = ldchunk(cbase + 4 * (size_t)HW, 0);
    if (C > 256) {
        t0[1]  = ldchunk(cbase, 1);
        pv1[1] = ldchunk(cbase + (size_t)HW, 1);
        pv2[1] = ldchunk(cbase + 2 * (size_t)HW, 1);
        pv3[1] = ldchunk(cbase + 3 * (size_t)HW, 1);
        pv0[1] = ldchunk(cbase + 4 * (size_t)HW, 1);
    }
    stchunk(lds[0], 0, t0[0]);
    if (C > 256) stchunk(lds[0], 1, t0[1]);
    WG_BARRIER_LDS();

    // Per iteration c: commit ch c+1 (loads issued at iter c-4) into
    // buf (c+1)&1; issue loads for ch c+5 into the set just freed;
    // compute ch c from buf c&1; barrier (lgkm-only, loads stay in flight).
#define ITER(k, PV)                                                     \
    {                                                                   \
        const int c = cc + (k);                                         \
        if (c + 1 < CGC) {                                              \
            float* dst = lds[((k) + 1) & 1];                            \
            stchunk(dst, 0, PV[0]);                                     \
            if (C > 256) stchunk(dst, 1, PV[1]);                        \
        }                                                               \
        if (c + 5 < CGC) {                                              \
            const float* pn = cbase + (size_t)(c + 5) * HW;             \
            PV[0] = ldchunk(pn, 0);                                     \
            if (C > 256) PV[1] = ldchunk(pn, 1);                        \
        }                                                               \
        if (t < 196) {                                                  \
            const float* L = lds[(k) & 1];                              \
            float v00 = L[p0];                                          \
            float v01 = L[p0 + 1];                                      \
            float v10 = L[p1];                                          \
            float v11 = L[p1 + 1];                                      \
            float val = vall ? (v00 * w00 + v01 * w01 + v10 * w10 +     \
                                v11 * w11)                              \
                             : 0.0f;                                    \
            val += __shfl_xor(val, 1, 64);                              \
            val += __shfl_xor(val, 2, 64);                              \
            if (s == 0) outk[c * NBINS + bin] = val * 0.25f;            \
        }                                                               \
        WG_BARRIER_LDS();                                               \
    }

    for (int cc = 0; cc < CGC; cc += 4) {
        ITER(0, pv1)
        ITER(1, pv2)
        ITER(2, pv3)
        ITER(3, pv0)
    }
#undef ITER
}

__global__ __launch_bounds__(256, 8)
void roi_align_fused(const float* __restrict__ f0, const float* __restrict__ f1,
                     const float* __restrict__ f2, const float* __restrict__ f3,
                     const float* __restrict__ rois,
                     float* __restrict__ out)
{
    __shared__ __align__(16) float lds[2][LDS_N];   // LDS_N*4 % 16 == 0 -> both bufs 16B-aligned

    const int k = blockIdx.x;
    const int g = blockIdx.y;
    const int t = threadIdx.x;

    float rb   = rois[k * 5 + 0];
    float rix1 = rois[k * 5 + 1];
    float riy1 = rois[k * 5 + 2];
    float rix2 = rois[k * 5 + 3];
    float riy2 = rois[k * 5 + 4];

    float scale = sqrtf((rix2 - rix1 + 1.0f) * (riy2 - riy1 + 1.0f));
    int lvl = (int)floorf(log2f(scale * (1.0f / 56.0f) + 1e-6f));
    lvl = lvl < 0 ? 0 : (lvl > 3 ? 3 : lvl);

    float ss = 1.0f / (float)(4 << lvl);
    float x1 = rix1 * ss, y1 = riy1 * ss;
    float rw = fmaxf(rix2 * ss - x1, 1.0f);
    float rh = fmaxf(riy2 * ss - y1, 1.0f);
    float bw = rw * (1.0f / OUT_SZ);
    float bh = rh * (1.0f / OUT_SZ);
    const int H = 800  >> (2 + lvl);
    const int W = 1216 >> (2 + lvl);

    const float* fb = (lvl == 0) ? f0 : (lvl == 1) ? f1 : (lvl == 2) ? f2 : f3;
    const int HW  = H * W;
    const int TOT = 2 * NCH * HW;
    const int base_off = ((int)rb * NCH + g * CGC) * HW;
    const float* cbase = fb + base_off;
    float* outk = out + ((size_t)k * NCH + (size_t)(g * CGC)) * NBINS;

    if (W & 3) {   // level 3 (W=38, HW=950): only 8B alignment -> float2 chunks
        int CLrel = TOT - base_off - (CGC - 1) * HW - 2;
        roi_group<1>(cbase, CLrel, HW, H, W, x1, y1, bw, bh, t, outk, lds);
    } else {       // levels 0-2: 16B-aligned float4 chunks
        int CLrel = TOT - base_off - (CGC - 1) * HW - 4;
        roi_group<2>(cbase, CLrel, HW, H, W, x1, y1, bw, bh, t, outk, lds);
    }
}

extern "C" void kernel_launch(void* const* d_in, const int* in_sizes, int n_in,
                              void* d_out, int out_size, void* d_ws, size_t ws_size,
                              hipStream_t stream)
{
    const float* f0   = (const float*)d_in[0];
    const float* f1   = (const float*)d_in[1];
    const float* f2   = (const float*)d_in[2];
    const float* f3   = (const float*)d_in[3];
    const float* rois = (const float*)d_in[4];
    float* out = (float*)d_out;

    int K = in_sizes[4] / 5;
    if (K <= 0) return;

    roi_align_fused<<<dim3(K, NGROUPS), 256, 0, stream>>>(f0, f1, f2, f3, rois, out);
}

// Round 3
// 304.848 us; speedup vs baseline: 1.0042x; 1.0042x over previous
//
#include <hip/hip_runtime.h>
#include <math.h>

// SingleRoIExtractor: 4-level FPN RoIAlign (mmdet legacy, aligned=False)
// R3: direct-gather rewrite. R0-R2 evidence: LDS-staged version is stuck at
// ~157us/dispatch regardless of prefetch depth (2 vs 4) or barrier vmcnt
// semantics (drain vs lgkm-only) -> bottleneck is the per-channel
// ds_write->barrier->ds_read round-trip + 4-wave convoy itself, not load
// latency. This version deletes LDS and barriers entirely:
//   block = (roi, 64-channel group), wave w owns channels w, w+4, ...,
//   lane = bin (49 of 64 active). Each lane reads its 16 bilinear corners
//   (4 rows x 2 cols x 2 adjacent floats) straight from global; L1 serves
//   the corner overlap (patch ~1.4KB << 32KB L1), L2/HBM line traffic is
//   identical to the staged version (same patch lines touched).
// Edge semantics folded into clamps: x0=min(floor(xc),W-2), lx=xc-x0 in
// [0,1] (xc=W-1 -> lx=1.0 selects column W-1 exactly); same for y. All
// addresses in-plane; invalid samples (outside [-1,W]) masked by wv=0.
// No barriers -> waves fully independent, latency hidden by 24+ waves/CU
// plus 16-deep per-wave load ILP.

#define OUT_SZ 7
#define NCH 256
#define NBINS 49
#define NGROUPS 4

__global__ __launch_bounds__(256, 6)
void roi_align_direct(const float* __restrict__ f0, const float* __restrict__ f1,
                      const float* __restrict__ f2, const float* __restrict__ f3,
                      const float* __restrict__ rois,
                      float* __restrict__ out)
{
    const int k = blockIdx.x;
    const int g = blockIdx.y;
    const int t = threadIdx.x;
    const int w    = t >> 6;   // wave id 0..3
    const int lane = t & 63;

    float rb   = rois[k * 5 + 0];
    float rix1 = rois[k * 5 + 1];
    float riy1 = rois[k * 5 + 2];
    float rix2 = rois[k * 5 + 3];
    float riy2 = rois[k * 5 + 4];

    float scale = sqrtf((rix2 - rix1 + 1.0f) * (riy2 - riy1 + 1.0f));
    int lvl = (int)floorf(log2f(scale * (1.0f / 56.0f) + 1e-6f));
    lvl = lvl < 0 ? 0 : (lvl > 3 ? 3 : lvl);

    float ss = 1.0f / (float)(4 << lvl);
    float x1 = rix1 * ss, y1 = riy1 * ss;
    float rw = fmaxf(rix2 * ss - x1, 1.0f);
    float rh = fmaxf(riy2 * ss - y1, 1.0f);
    float bw = rw * (1.0f / OUT_SZ);
    float bh = rh * (1.0f / OUT_SZ);
    const int H = 800  >> (2 + lvl);
    const int W = 1216 >> (2 + lvl);
    const float fH = (float)H, fW = (float)W;
    const float* fb = (lvl == 0) ? f0 : (lvl == 1) ? f1 : (lvl == 2) ? f2 : f3;
    const int HW = H * W;

    if (lane >= NBINS) return;   // no barriers anywhere -> early exit is safe
    const int bin = lane;
    const int oy = bin / OUT_SZ;
    const int ox = bin - oy * OUT_SZ;

    // ---- per-lane sample geometry (computed once, reused for 16 channels) ----
    float lx[2], fvx[2]; int cx[2];
#pragma unroll
    for (int j = 0; j < 2; ++j) {
        float xs = x1 + ((float)(2 * ox + j) + 0.5f) * 0.5f * bw;
        fvx[j] = (xs >= -1.0f && xs <= fW) ? 1.0f : 0.0f;
        float xc = fminf(fmaxf(xs, 0.0f), fW - 1.0f);
        int x0 = (int)floorf(xc);
        x0 = min(x0, W - 2);            // xc=W-1 -> lx=1.0 selects col W-1
        lx[j] = xc - (float)x0;
        cx[j] = x0;
    }
    float ly[2], fvy[2]; int ry[2];
#pragma unroll
    for (int i = 0; i < 2; ++i) {
        float ysv = y1 + ((float)(2 * oy + i) + 0.5f) * 0.5f * bh;
        fvy[i] = (ysv >= -1.0f && ysv <= fH) ? 1.0f : 0.0f;
        float yc = fminf(fmaxf(ysv, 0.0f), fH - 1.0f);
        int y0 = (int)floorf(yc);
        y0 = min(y0, H - 2);            // yc=H-1 -> ly=1.0 selects row H-1
        ly[i] = yc - (float)y0;
        ry[i] = y0;
    }
    float wv00 = fvy[0] * fvx[0], wv01 = fvy[0] * fvx[1];
    float wv10 = fvy[1] * fvx[0], wv11 = fvy[1] * fvx[1];

    // 8 element offsets: rows {ry0, ry0+1, ry1, ry1+1} x cols {cx0, cx1}.
    // q = 2*r + j. All in-plane: rows <= H-1, cols cx..cx+1 <= W-1.
    int off[8];
#pragma unroll
    for (int r = 0; r < 4; ++r) {
        int row = ry[r >> 1] + (r & 1);
        off[2 * r + 0] = row * W + cx[0];
        off[2 * r + 1] = row * W + cx[1];
    }

    const int ch0 = g * 64 + w;         // this wave's first channel
    const float* chp = fb + (size_t)((int)rb * NCH + ch0) * HW;
    float* outp = out + ((size_t)k * NCH + ch0) * NBINS + bin;

#pragma unroll 2
    for (int i = 0; i < 16; ++i) {      // channels ch0, ch0+4, ..., ch0+60
        float v0[8], v1[8];
#pragma unroll
        for (int q = 0; q < 8; ++q) {
            v0[q] = chp[off[q]];
            v1[q] = chp[off[q] + 1];
        }
        float h[8];
#pragma unroll
        for (int q = 0; q < 8; ++q)
            h[q] = fmaf(lx[q & 1], v1[q] - v0[q], v0[q]);   // x-interp

        // rows: h[0],h[1]=ry0 ; h[2],h[3]=ry0+1 ; h[4],h[5]=ry1 ; h[6],h[7]=ry1+1
        float s00 = fmaf(ly[0], h[2] - h[0], h[0]);
        float s01 = fmaf(ly[0], h[3] - h[1], h[1]);
        float s10 = fmaf(ly[1], h[6] - h[4], h[4]);
        float s11 = fmaf(ly[1], h[7] - h[5], h[5]);

        float acc = wv00 * s00 + wv01 * s01 + wv10 * s10 + wv11 * s11;
        *outp = acc * 0.25f;

        chp  += 4 * (size_t)HW;
        outp += 4 * NBINS;
    }
}

extern "C" void kernel_launch(void* const* d_in, const int* in_sizes, int n_in,
                              void* d_out, int out_size, void* d_ws, size_t ws_size,
                              hipStream_t stream)
{
    const float* f0   = (const float*)d_in[0];
    const float* f1   = (const float*)d_in[1];
    const float* f2   = (const float*)d_in[2];
    const float* f3   = (const float*)d_in[3];
    const float* rois = (const float*)d_in[4];
    float* out = (float*)d_out;

    int K = in_sizes[4] / 5;
    if (K <= 0) return;

    roi_align_direct<<<dim3(K, NGROUPS), 256, 0, stream>>>(f0, f1, f2, f3, rois, out);
}